// Round 6
// baseline (119.539 us; speedup 1.0000x reference)
//
#include <hip/hip_runtime.h>

// IMM loss: G=8192 groups of M=16 particles, D=64 dims, fp32.
// terms = Lap(x,x)+Lap(y,y)-2*Lap(x,y), Lap = exp(-ws[j]*max(||a-b||,EPS)/D).
//
// R6: inverted loop nest. R5's VGPR_Count=36 proved the compiler sank the
// row loads into every offset body (16x redundant L1 loads, vmcnt chains ->
// VALUBusy 42%). Now: 31 persistent per-offset accumulators; each loaded
// float4 is consumed by ALL 16 offsets immediately at its one load site,
// then dies. Nothing to re-materialize. Live set ~50 regs.
//
// Lane map (kept from R5, loads coalesced): one wave per group; lane=q*16+j
// holds dims [16q,16q+16) of particle j -> wave covers one contiguous 4 KB
// block per tensor. Partner (j+o)&15 has same q -> DPP row_ror works.
// Per-offset 16-dim partials are butterflied across q (xor 16/32) in the
// epilogue; epilogue replicated across q-rows, /4 folded into final scale.

#define EPS_D 0.006f

// Rotate right within each 16-lane row by O (compile-time 1..15):
// lane q*16+j receives lane q*16+((j+O)&15). Verified exact (R2-R5 absmax 0.0).
#define ROT(v, O) __int_as_float(__builtin_amdgcn_update_dpp(              \
        0, __float_as_int(v), 0x120 + (O), 0xF, 0xF, false))

// Sum the 4 q-row partials (lanes j, j+16, j+32, j+48): all lanes get total.
__device__ __forceinline__ float red4(float p) {
    p += __shfl_xor(p, 16, 64);
    p += __shfl_xor(p, 32, 64);
    return p;
}

// One dim value pair (xv, yv): update all 31 accumulators.
#define UPD_FULL(O) {                                                      \
    float tx = ROT(xv, O) - xv;   /* xr - x (single use -> sub_dpp) */     \
    float tz = ROT(yv, O) - xv;   /* yr - x */                             \
    float ty = tz + dl;           /* yr - y */                             \
    fxx[(O)-1] = fmaf(tx, tx, fxx[(O)-1]);                                 \
    fyy[(O)-1] = fmaf(ty, ty, fyy[(O)-1]);                                 \
    fxy[(O)-1] = fmaf(tz, tz, fxy[(O)-1]); }

#define UPD_XY(O) {                                                        \
    float tz = ROT(yv, O) - xv;                                            \
    gxy[(O)-8] = fmaf(tz, tz, gxy[(O)-8]); }

#define DIM_STEP(XV, YV) {                                                 \
    const float xv = (XV), yv = (YV);                                      \
    const float dl = xv - yv;                                              \
    gxy[0] = fmaf(dl, dl, gxy[0]);          /* xy offset 0: (y-x)^2 */     \
    UPD_FULL(1) UPD_FULL(2) UPD_FULL(3) UPD_FULL(4)                        \
    UPD_FULL(5) UPD_FULL(6) UPD_FULL(7) UPD_FULL(8)                        \
    UPD_XY(9) UPD_XY(10) UPD_XY(11) UPD_XY(12)                             \
    UPD_XY(13) UPD_XY(14) UPD_XY(15) }

__global__ __launch_bounds__(256, 4)
void imm_loss_kernel(const float* __restrict__ ys_t,
                     const float* __restrict__ ys_r,
                     const float* __restrict__ w_scale,
                     const float* __restrict__ time_w,
                     float* __restrict__ partials)
{
    const int tid  = threadIdx.x;
    const int lane = tid & 63;
    const int wave = tid >> 6;
    const int q    = lane >> 4;          // dim slice [16q, 16q+16)
    const int j    = lane & 15;          // particle index
    const int g    = blockIdx.x * 4 + wave;   // group id

    const size_t base = (size_t)g * 1024 + j * 64 + q * 16;
    const float4* xp = reinterpret_cast<const float4*>(ys_t + base);
    const float4* yp = reinterpret_cast<const float4*>(ys_r + base);

    // Per-offset squared-distance accumulators (persistent across dims).
    float fxx[8], fyy[8], fxy[8], gxy[8];
    #pragma unroll
    for (int i = 0; i < 8; ++i) { fxx[i] = 0.f; fyy[i] = 0.f; fxy[i] = 0.f; gxy[i] = 0.f; }

    // Stream 16 dims as 4 float4 pairs; each value consumed fully on arrival.
    #pragma unroll
    for (int t = 0; t < 4; ++t) {
        float4 xv4 = xp[t];
        float4 yv4 = yp[t];
        DIM_STEP(xv4.x, yv4.x)
        DIM_STEP(xv4.y, yv4.y)
        DIM_STEP(xv4.z, yv4.z)
        DIM_STEP(xv4.w, yv4.w)
    }

    const float s_j = w_scale[g * 16 + j] * (1.0f / 64.0f);  // ws[j]/D
    const float tw  = time_w[g * 16];                        // per-group weight

    // xx + yy diagonals (d=0 clamps to EPS).
    float acc = 2.0f * __expf(-s_j * EPS_D);

    // xy offset 0.
    {
        float p0 = red4(gxy[0]);
        acc -= 2.0f * __expf(-s_j * fmaxf(sqrtf(p0), EPS_D));
    }

    // Full pair offsets 1..8: xx & yy via symmetry (ordered (j,k) uses s_j,
    // (k,j) uses s_k; o=8 hit from both endpoints -> weight 0.5) + xy.
#define EPI_FULL(O, W) {                                                   \
        float pxx = red4(fxx[(O)-1]);                                      \
        float pyy = red4(fyy[(O)-1]);                                      \
        float pxy = red4(fxy[(O)-1]);                                      \
        const float s_k = ROT(s_j, O);                                     \
        const float ddx = fmaxf(sqrtf(pxx), EPS_D);                        \
        const float ddy = fmaxf(sqrtf(pyy), EPS_D);                        \
        const float ddz = fmaxf(sqrtf(pxy), EPS_D);                        \
        acc += (W) * (__expf(-s_j * ddx) + __expf(-s_k * ddx));            \
        acc += (W) * (__expf(-s_j * ddy) + __expf(-s_k * ddy));            \
        acc -= 2.0f * __expf(-s_j * ddz); }

#define EPI_XY(O) {                                                        \
        float pxy = red4(gxy[(O)-8]);                                      \
        acc -= 2.0f * __expf(-s_j * fmaxf(sqrtf(pxy), EPS_D)); }

    EPI_FULL(1, 1.0f) EPI_FULL(2, 1.0f) EPI_FULL(3, 1.0f) EPI_FULL(4, 1.0f)
    EPI_FULL(5, 1.0f) EPI_FULL(6, 1.0f) EPI_FULL(7, 1.0f) EPI_FULL(8, 0.5f)
    EPI_XY(9) EPI_XY(10) EPI_XY(11) EPI_XY(12)
    EPI_XY(13) EPI_XY(14) EPI_XY(15)

    // acc replicated across 4 q-rows; extra x4 folded into inv_scale.
    float val = acc * tw;
    #pragma unroll
    for (int off = 32; off; off >>= 1)
        val += __shfl_xor(val, off, 64);

    __shared__ float smem[4];
    if (lane == 0) smem[wave] = val;
    __syncthreads();
    if (tid == 0)
        partials[blockIdx.x] = smem[0] + smem[1] + smem[2] + smem[3];
}

__global__ void imm_reduce_kernel(const float* __restrict__ part, int n,
                                  float inv_scale, float* __restrict__ out)
{
    const int tid = threadIdx.x;
    float v = 0.f;
    for (int i = tid; i < n; i += 256) v += part[i];
    #pragma unroll
    for (int off = 32; off; off >>= 1) v += __shfl_xor(v, off, 64);
    __shared__ float s[4];
    if ((tid & 63) == 0) s[tid >> 6] = v;
    __syncthreads();
    if (tid == 0) out[0] = (s[0] + s[1] + s[2] + s[3]) * inv_scale;
}

extern "C" void kernel_launch(void* const* d_in, const int* in_sizes, int n_in,
                              void* d_out, int out_size, void* d_ws, size_t ws_size,
                              hipStream_t stream)
{
    const float* ys_t = (const float*)d_in[0];
    const float* ys_r = (const float*)d_in[1];
    const float* wsc  = (const float*)d_in[2];
    const float* twp  = (const float*)d_in[3];
    float* out      = (float*)d_out;
    float* partials = (float*)d_ws;

    const int B = in_sizes[2];      // 131072
    const int G = B / 16;           // 8192 groups
    const int blocks = G / 4;       // 1 group per wave, 4 waves per block

    imm_loss_kernel<<<blocks, 256, 0, stream>>>(ys_t, ys_r, wsc, twp, partials);

    // 1/(M*M*G) with the extra /4 for q-row replication of acc.
    const float inv_scale = 1.0f / (4.0f * 256.0f * (float)G);
    imm_reduce_kernel<<<1, 256, 0, stream>>>(partials, blocks, inv_scale, out);
}